// Round 7
// baseline (224.096 us; speedup 1.0000x reference)
//
#include <hip/hip_runtime.h>

typedef __bf16 bhalf;
typedef bhalf bhalf8 __attribute__((ext_vector_type(8)));
typedef float f32x4 __attribute__((ext_vector_type(4)));
typedef unsigned short u16;
typedef u16 u16x8 __attribute__((ext_vector_type(8)));

__device__ __forceinline__ u16 f2bf(float f) {
  union { float f; unsigned u; } v; v.f = f;
  unsigned r = v.u + 0x7FFFu + ((v.u >> 16) & 1u);
  return (u16)(r >> 16);
}

// XOR swizzle keyed on bits 7-9; involution; <=2-way banks on frag reads.
__device__ __forceinline__ int swz(int L) { return L ^ (((L >> 7) & 7) << 4); }

#define GLL16(gp, lp) __builtin_amdgcn_global_load_lds( \
    (const __attribute__((address_space(1))) unsigned int*)(gp), \
    (__attribute__((address_space(3))) unsigned int*)(lp), 16, 0, 0)

#define W0E (512 * 832)
#define W1E (256 * 512)
#define W2E (16 * 256)

__global__ __launch_bounds__(256) void cvt_weights(
    const float* __restrict__ W0, const float* __restrict__ W1,
    const float* __restrict__ W2,
    u16* __restrict__ W0b, u16* __restrict__ W1b, u16* __restrict__ W2b)
{
  int i = blockIdx.x * 256 + threadIdx.x;
  if (i < W0E) {
    int r = i / 832, k = i - r * 832;
    W0b[i] = (k < 784) ? f2bf(W0[r * 784 + k]) : (u16)0;
    return;
  }
  i -= W0E;
  if (i < W1E) { W1b[i] = f2bf(W1[i]); return; }
  i -= W1E;
  if (i < W2E) {
    int r = i >> 8, c = i & 255;
    W2b[i] = (r < 10) ? f2bf(W2[r * 256 + c]) : (u16)0;
  }
}

// ABLATION of the 70.3us r5-config gemm1 (128x128, BK=32, 4 waves, dbuf, drain-all).
// V=0 full (real m1) | V=1 no A(x) global loads | V=2 no B gll | V=3 no frag-reads/MFMA
// V=5 no barrier/drain. Diagnostic variants write garbage to m1; V0 (dispatched last)
// overwrites every byte -> deterministic output.
template<int V>
__global__ __launch_bounds__(256, 4) void gemm1_abl(
    const float* __restrict__ x, const u16* __restrict__ Wb, u16* __restrict__ Cp)
{
  constexpr bool LOADX   = (V != 1);
  constexpr bool LOADB   = (V != 2);
  constexpr bool COMPUTE = (V != 3);
  constexpr bool BAR     = (V != 5);

  __shared__ u16 As[2][4096];   // 128 x 32 bf16 = 8 KiB per buffer
  __shared__ u16 Bs[2][4096];
  const int t = threadIdx.x, w = t >> 6, lane = t & 63;
  const int bid = blockIdx.x;
  const int rt = (bid & 7) + ((bid >> 5) << 3);   // XCD-aware
  const int ct = (bid >> 3) & 3;
  const size_t rbase = (size_t)rt * 128, cbase = (size_t)ct * 128;
  const int wr = w >> 1, wc = w & 1, fr = lane & 15, fg = lane >> 4;

  int aOff[4], bOff[4];
#pragma unroll
  for (int i = 0; i < 4; ++i) aOff[i] = swz((wr * 64 + i * 16 + fr) * 64 + fg * 16);
#pragma unroll
  for (int j = 0; j < 4; ++j) bOff[j] = swz((wc * 64 + j * 16 + fr) * 64 + fg * 16);

  const u16* bSrc[2]; int bDst[2];
#pragma unroll
  for (int i = 0; i < 2; ++i) {
    int Dl = (w * 128 + i * 64 + lane) * 16;
    int Ul = swz(Dl);
    bSrc[i] = Wb + (cbase + (Ul >> 6)) * 832 + ((Ul & 63) >> 1);
    bDst[i] = (w * 128 + i * 64) * 16;
  }

  int aRow[2], aKe[2], aDst[2];
#pragma unroll
  for (int c = 0; c < 2; ++c) {
    int P = c * 4096 + t * 16;
    int Lg = swz(P);
    aRow[c] = Lg >> 6; aKe[c] = (Lg & 63) >> 1; aDst[c] = P;
  }

  f32x4 acc[4][4];
#pragma unroll
  for (int i = 0; i < 4; ++i)
#pragma unroll
    for (int j = 0; j < 4; ++j) acc[i][j] = (f32x4){0.f, 0.f, 0.f, 0.f};

  f32x4 areg[2][2];
#pragma unroll
  for (int c = 0; c < 2; ++c) { areg[c][0] = (f32x4){0,0,0,0}; areg[c][1] = (f32x4){0,0,0,0}; }

  // prologue: tile 0
  if constexpr (LOADX) {
#pragma unroll
    for (int c = 0; c < 2; ++c) {
      const float* p = x + (rbase + aRow[c]) * (size_t)784 + aKe[c];
      areg[c][0] = *(const f32x4*)p; areg[c][1] = *(const f32x4*)(p + 4);
    }
  }
  if constexpr (LOADB) {
#pragma unroll
    for (int i = 0; i < 2; ++i) GLL16(bSrc[i], (char*)Bs[0] + bDst[i]);
  }

  for (int tt = 0; tt < 26; ++tt) {
    const int cur = tt & 1;
    // convert + write A tile (compiler auto-waits pending A loads)
#pragma unroll
    for (int c = 0; c < 2; ++c) {
      u16x8 v;
#pragma unroll
      for (int j = 0; j < 4; ++j) { v[j] = f2bf(areg[c][0][j]); v[4 + j] = f2bf(areg[c][1][j]); }
      *(u16x8*)((char*)As[cur] + aDst[c]) = v;
    }
    if constexpr (BAR) {
      asm volatile("s_waitcnt vmcnt(0)" ::: "memory");
      __syncthreads();
    } else {
      __builtin_amdgcn_sched_barrier(0);
    }

    if (tt < 25) {
      const int k0 = (tt + 1) * 32;
      if constexpr (LOADX) {
#pragma unroll
        for (int c = 0; c < 2; ++c) {
          int k = k0 + aKe[c];
          int koff = (k < 784) ? k : 0;
          const float* p = x + (rbase + aRow[c]) * (size_t)784 + koff;
          areg[c][0] = *(const f32x4*)p; areg[c][1] = *(const f32x4*)(p + 4);
        }
      }
      if constexpr (LOADB) {
#pragma unroll
        for (int i = 0; i < 2; ++i) GLL16(bSrc[i] + k0, (char*)Bs[cur ^ 1] + bDst[i]);
      }
    }

    if constexpr (COMPUTE) {
      bhalf8 af[4], bfv[4];
#pragma unroll
      for (int i = 0; i < 4; ++i) af[i] = *(const bhalf8*)((const char*)As[cur] + aOff[i]);
#pragma unroll
      for (int j = 0; j < 4; ++j) bfv[j] = *(const bhalf8*)((const char*)Bs[cur] + bOff[j]);
#pragma unroll
      for (int i = 0; i < 4; ++i)
#pragma unroll
        for (int j = 0; j < 4; ++j)
          acc[i][j] = __builtin_amdgcn_mfma_f32_16x16x32_bf16(af[i], bfv[j], acc[i][j], 0, 0, 0);
    }
  }

  if constexpr (!COMPUTE) {
    // anti-DCE keep: touch both LDS tiles so staging can't be eliminated (rule #17)
    int z = (int)As[0][t] + (int)As[1][t] + (int)Bs[0][t] + (int)Bs[1][t];
    asm volatile("" :: "v"(z));
  }

#pragma unroll
  for (int i = 0; i < 4; ++i)
#pragma unroll
    for (int j = 0; j < 4; ++j)
#pragma unroll
      for (int q = 0; q < 4; ++q) {
        size_t row = rbase + wr * 64 + i * 16 + fg * 4 + q;
        size_t col = cbase + wc * 64 + j * 16 + fr;
        float vv = acc[i][j][q];
        vv = vv > 0.f ? vv : 0.f;
        Cp[row * 512 + col] = f2bf(vv);
      }
}

// Fused layers 2+3 (unchanged from the 70.3us round): 64 rows x full 256 cols,
// 8 waves (2x4), BK=32, 16 steps, all-GLL dbuf, 2 blocks/CU.
__global__ __launch_bounds__(512, 4) void gemm23(
    const u16* __restrict__ m1, const u16* __restrict__ W1b,
    const u16* __restrict__ W2b, float* __restrict__ out)
{
  __shared__ u16 pool[20480];    // A dbuf 2x4KB @0 | B dbuf 2x16KB @8192; reused as m2 [64][264]
  __shared__ u16 W2s[16][264];
  const int t = threadIdx.x, w = t >> 6, lane = t & 63;
  const size_t rbase = (size_t)blockIdx.x * 64;
  const int wr = w >> 2, wc = w & 3, fr = lane & 15, fg = lane >> 4;

  {
    int r = t >> 5, kc = (t & 31) * 8;
    *(int4*)&W2s[r][kc] = *(const int4*)(W2b + r * 256 + kc);
  }

  int aOff[2], bOff[4];
#pragma unroll
  for (int i = 0; i < 2; ++i) aOff[i] = swz((wr * 32 + i * 16 + fr) * 64 + fg * 16);
#pragma unroll
  for (int j = 0; j < 4; ++j) bOff[j] = swz((wc * 64 + j * 16 + fr) * 64 + fg * 16);

  const u16* aSrc = nullptr; int aDst = 0;
  if (w < 4) {
    int Dl = (w * 64 + lane) * 16;
    int Ul = swz(Dl);
    aSrc = m1 + (rbase + (Ul >> 6)) * 512 + ((Ul & 63) >> 1);
    aDst = (w * 64) * 16;
  }
  const u16* bSrc[2]; int bDst[2];
#pragma unroll
  for (int i = 0; i < 2; ++i) {
    int Dl = (w * 128 + i * 64 + lane) * 16;
    int Ul = swz(Dl);
    bSrc[i] = W1b + (Ul >> 6) * 512 + ((Ul & 63) >> 1);
    bDst[i] = 8192 + (w * 128 + i * 64) * 16;
  }

  f32x4 acc[2][4];
#pragma unroll
  for (int i = 0; i < 2; ++i)
#pragma unroll
    for (int j = 0; j < 4; ++j) acc[i][j] = (f32x4){0.f, 0.f, 0.f, 0.f};

  if (w < 4) GLL16(aSrc, (char*)pool + aDst);
#pragma unroll
  for (int i = 0; i < 2; ++i) GLL16(bSrc[i], (char*)pool + bDst[i]);

  for (int tt = 0; tt < 16; ++tt) {
    const int cur = tt & 1;
    const char* Asc = (const char*)pool + cur * 4096;
    const char* Bsc = (const char*)pool + 8192 + cur * 16384;
    asm volatile("s_waitcnt vmcnt(0)" ::: "memory");
    __syncthreads();

    if (tt < 15) {
      const int k0 = (tt + 1) * 32;
      if (w < 4) GLL16(aSrc + k0, (char*)pool + (cur ^ 1) * 4096 + aDst);
#pragma unroll
      for (int i = 0; i < 2; ++i)
        GLL16(bSrc[i] + k0, (char*)pool + (cur ^ 1) * 16384 + bDst[i]);
    }

    bhalf8 af[2], bfv[4];
#pragma unroll
    for (int i = 0; i < 2; ++i) af[i] = *(const bhalf8*)(Asc + aOff[i]);
#pragma unroll
    for (int j = 0; j < 4; ++j) bfv[j] = *(const bhalf8*)(Bsc + bOff[j]);
#pragma unroll
    for (int i = 0; i < 2; ++i)
#pragma unroll
      for (int j = 0; j < 4; ++j)
        acc[i][j] = __builtin_amdgcn_mfma_f32_16x16x32_bf16(af[i], bfv[j], acc[i][j], 0, 0, 0);
  }

  __syncthreads();
#pragma unroll
  for (int i = 0; i < 2; ++i)
#pragma unroll
    for (int j = 0; j < 4; ++j)
#pragma unroll
      for (int q = 0; q < 4; ++q) {
        int row = wr * 32 + i * 16 + fg * 4 + q;
        int col = wc * 64 + j * 16 + fr;
        float vv = acc[i][j][q];
        vv = vv > 0.f ? vv : 0.f;
        pool[row * 264 + col] = f2bf(vv);
      }
  __syncthreads();

  if (w < 4) {
    f32x4 acc3 = (f32x4){0.f, 0.f, 0.f, 0.f};
    const int arow = w * 16 + fr;
#pragma unroll
    for (int ks = 0; ks < 8; ++ks) {
      bhalf8 a = *(const bhalf8*)&pool[arow * 264 + ks * 32 + fg * 8];
      bhalf8 b = *(const bhalf8*)&W2s[fr][ks * 32 + fg * 8];
      acc3 = __builtin_amdgcn_mfma_f32_16x16x32_bf16(a, b, acc3, 0, 0, 0);
    }
    if (fr < 10) {
#pragma unroll
      for (int q = 0; q < 4; ++q) {
        size_t row = rbase + w * 16 + fg * 4 + q;
        float vv = acc3[q];
        out[row * 10 + fr] = vv > 0.f ? vv : 0.f;
      }
    }
  }
}

extern "C" void kernel_launch(void* const* d_in, const int* in_sizes, int n_in,
                              void* d_out, int out_size, void* d_ws, size_t ws_size,
                              hipStream_t stream) {
  const float* x  = (const float*)d_in[0];
  const float* W0 = (const float*)d_in[1];
  const float* W1 = (const float*)d_in[2];
  const float* W2 = (const float*)d_in[3];
  float* out = (float*)d_out;

  char* ws = (char*)d_ws;
  u16* m1  = (u16*)(ws);                    // 32768x512 bf16 = 33554432 B
  u16* W0b = (u16*)(ws + 33554432);         // 512x832 = 851968 B
  u16* W1b = (u16*)(ws + 34406400);         // 256x512 = 262144 B
  u16* W2b = (u16*)(ws + 34668544);         // 16x256  = 8192 B

  cvt_weights<<<dim3((W0E + W1E + W2E + 255) / 256), dim3(256), 0, stream>>>(
      W0, W1, W2, W0b, W1b, W2b);

  // ABLATION (diagnostic; each fully overwritten by the final real V0):
  gemm1_abl<1><<<dim3(1024), dim3(256), 0, stream>>>(x, W0b, m1);  // no x loads
  gemm1_abl<2><<<dim3(1024), dim3(256), 0, stream>>>(x, W0b, m1);  // no W0 gll
  gemm1_abl<3><<<dim3(1024), dim3(256), 0, stream>>>(x, W0b, m1);  // no frag-read/MFMA
  gemm1_abl<5><<<dim3(1024), dim3(256), 0, stream>>>(x, W0b, m1);  // no barrier/drain
  gemm1_abl<0><<<dim3(1024), dim3(256), 0, stream>>>(x, W0b, m1);  // REAL

  gemm23<<<dim3(512), dim3(512), 0, stream>>>(m1, W1b, W2b, out);
}

// Round 8
// 65.294 us; speedup vs baseline: 3.4321x; 3.4321x over previous
//
#include <hip/hip_runtime.h>

typedef __bf16 bhalf;
typedef bhalf bhalf8 __attribute__((ext_vector_type(8)));
typedef float f32x4 __attribute__((ext_vector_type(4)));
typedef unsigned short u16;
typedef u16 u16x8 __attribute__((ext_vector_type(8)));

__device__ __forceinline__ u16 f2bf(float f) {
  union { float f; unsigned u; } v; v.f = f;
  unsigned r = v.u + 0x7FFFu + ((v.u >> 16) & 1u);
  return (u16)(r >> 16);
}

// XOR swizzle keyed on bits 7-9; involution; <=2-way banks on frag reads (r5: 0 conflicts).
__device__ __forceinline__ int swz(int L) { return L ^ (((L >> 7) & 7) << 4); }

#define GLL16(gp, lp) __builtin_amdgcn_global_load_lds( \
    (const __attribute__((address_space(1))) unsigned int*)(gp), \
    (__attribute__((address_space(3))) unsigned int*)(lp), 16, 0, 0)

#define SB() __builtin_amdgcn_sched_barrier(0)

// W0: [512][784] f32 -> bf16 [512][896] zero-pad; W1: [256][512]; W2: [10][256]->[16][256].
#define KP0 896
#define W0E (512 * KP0)
#define W1E (256 * 512)
#define W2E (16 * 256)

__global__ __launch_bounds__(256) void cvt_weights(
    const float* __restrict__ W0, const float* __restrict__ W1,
    const float* __restrict__ W2,
    u16* __restrict__ W0b, u16* __restrict__ W1b, u16* __restrict__ W2b)
{
  int i = blockIdx.x * 256 + threadIdx.x;
  if (i < W0E) {
    int r = i / KP0, k = i - r * KP0;
    W0b[i] = (k < 784) ? f2bf(W0[r * 784 + k]) : (u16)0;
    return;
  }
  i -= W0E;
  if (i < W1E) { W1b[i] = f2bf(W1[i]); return; }
  i -= W1E;
  if (i < W2E) {
    int r = i >> 8, c = i & 255;
    W2b[i] = (r < 10) ? f2bf(W2[r * 256 + c]) : (u16)0;
  }
}

// m1 = relu(x @ W0^T): 256x256 tile, BK=32, 8 waves (2Mx4N, wave tile 128x64),
// dbuf 64KB LDS, T3/T4 two-barrier K-step with counted vmcnt(6), T2 swizzle,
// T5 setprio, T1 XCD map. A: f32 reg-staged+cvt; B: gll pre-swizzled. 28 K-tiles.
__global__ __launch_bounds__(512) void gemm1_8p(
    const float* __restrict__ x, const u16* __restrict__ Wb, u16* __restrict__ Cp)
{
  __shared__ u16 lds[32768];    // bytes: A0 @0, A1 @16384, B0 @32768, B1 @49152
  const int t = threadIdx.x, w = t >> 6, lane = t & 63;
  const int bid = blockIdx.x;
  // XCD x = bid%8 owns rt x*16..x*16+15, ct pairs adjacent -> x-panel L2-shared.
  const int rt = (bid & 7) * 16 + (bid >> 4);
  const int ct = (bid >> 3) & 1;
  const size_t rbase = (size_t)rt * 256, cbase = (size_t)ct * 256;
  const int wr = w >> 2, wc = w & 3, fr = lane & 15, fg = lane >> 4;

  // fragment byte offsets within a 16KB tile (64B rows); m+4 frag = +4096
  int aO[4], bO[4];
#pragma unroll
  for (int m = 0; m < 4; ++m) aO[m] = swz((wr * 128 + m * 16 + fr) * 64 + fg * 16);
#pragma unroll
  for (int n = 0; n < 4; ++n) bO[n] = swz((wc * 64 + n * 16 + fr) * 64 + fg * 16);

  // B staging: 2 gll/wave; source pre-swizzled
  const u16* bSrc[2];
#pragma unroll
  for (int i = 0; i < 2; ++i) {
    int P = (w * 2 + i) * 1024 + lane * 16;
    int U = swz(P);
    bSrc[i] = Wb + (size_t)(cbase + (U >> 6)) * KP0 + ((U & 63) >> 1);
  }

  // A staging: 2 chunks/thread (16B bf16 dest = 8 f32 src each)
  const float* xRow[2]; int aKe[2];
#pragma unroll
  for (int c2 = 0; c2 < 2; ++c2) {
    int P = c2 * 8192 + t * 16;
    int U = swz(P);
    xRow[c2] = x + (size_t)(rbase + (U >> 6)) * 784;
    aKe[c2] = (U & 63) >> 1;
  }

  f32x4 acc[8][4];
#pragma unroll
  for (int m = 0; m < 8; ++m)
#pragma unroll
    for (int n = 0; n < 4; ++n) acc[m][n] = (f32x4){0.f, 0.f, 0.f, 0.f};

  f32x4 xr[2][2];
  bhalf8 bf[4], afA[4], afB[4];

  auto loadX = [&](int ttn) {
#pragma unroll
    for (int c2 = 0; c2 < 2; ++c2) {
      int gk = ttn * 32 + aKe[c2];
      const float* p = xRow[c2] + ((gk < 784) ? gk : 0);  // clamp: W0b zero-padded
      xr[c2][0] = *(const f32x4*)p; xr[c2][1] = *(const f32x4*)(p + 4);
    }
  };
  auto cvtW = [&](int aBaseOther) {
#pragma unroll
    for (int c2 = 0; c2 < 2; ++c2) {
      u16x8 v;
#pragma unroll
      for (int j = 0; j < 4; ++j) { v[j] = f2bf(xr[c2][0][j]); v[4 + j] = f2bf(xr[c2][1][j]); }
      *(u16x8*)((char*)lds + aBaseOther + c2 * 8192 + t * 16) = v;
    }
  };
  auto stageB = [&](int ttn, int bBaseT) {
#pragma unroll
    for (int i = 0; i < 2; ++i)
      GLL16(bSrc[i] + ttn * 32, (char*)lds + bBaseT + (w * 2 + i) * 1024);
  };
  auto rdB  = [&](int bB) {
#pragma unroll
    for (int n = 0; n < 4; ++n) bf[n] = *(const bhalf8*)((const char*)lds + bB + bO[n]);
  };
  auto rdA0 = [&](int aB) {
#pragma unroll
    for (int m = 0; m < 4; ++m) afA[m] = *(const bhalf8*)((const char*)lds + aB + aO[m]);
  };
  auto rdA1 = [&](int aB) {
#pragma unroll
    for (int m = 0; m < 4; ++m) afB[m] = *(const bhalf8*)((const char*)lds + aB + aO[m] + 4096);
  };
  auto mfmaLo = [&]() {
    __builtin_amdgcn_s_setprio(1);
#pragma unroll
    for (int m = 0; m < 4; ++m)
#pragma unroll
      for (int n = 0; n < 4; ++n)
        acc[m][n] = __builtin_amdgcn_mfma_f32_16x16x32_bf16(afA[m], bf[n], acc[m][n], 0, 0, 0);
    __builtin_amdgcn_s_setprio(0);
  };
  auto mfmaHi = [&]() {
    __builtin_amdgcn_s_setprio(1);
#pragma unroll
    for (int m = 0; m < 4; ++m)
#pragma unroll
      for (int n = 0; n < 4; ++n)
        acc[4 + m][n] = __builtin_amdgcn_mfma_f32_16x16x32_bf16(afB[m], bf[n], acc[4 + m][n], 0, 0, 0);
    __builtin_amdgcn_s_setprio(0);
  };

  // ---- prologue: tile0 staged, tile1 in flight ----
  loadX(0);
  stageB(0, 32768);
  cvtW(0);            // auto-waits x(0) (vmcnt(2): gll(0) keeps flying)
  loadX(1);
  stageB(1, 49152);
  asm volatile("s_waitcnt vmcnt(6) lgkmcnt(0)" ::: "memory"); SB();  // B(0) arrived, A0 written
  __builtin_amdgcn_s_barrier();

  // ---- steady loop: tiles 0..25 ----
  for (int tt = 0; tt < 26; ++tt) {
    const int c = tt & 1;
    const int aB = c << 14;             // A[c]
    const int bB = 32768 + (c << 14);   // B[c]
    // phase A
    rdB(bB); rdA0(aB);
    asm volatile("s_waitcnt lgkmcnt(0)" ::: "memory"); SB();
    mfmaLo();
    rdA1(aB);
    asm volatile("s_waitcnt lgkmcnt(0)" ::: "memory"); SB();
    __builtin_amdgcn_s_barrier();       // all waves done reading buf[c]
    // phase B
    cvtW(aB ^ 16384);                   // A(tt+1) -> other A buf (auto vmcnt(2))
    loadX(tt + 2);                      // x(tt+2) into freed regs
    stageB(tt + 2, bB);                 // B(tt+2) -> just-freed B[c]
    mfmaHi();
    asm volatile("s_waitcnt vmcnt(6) lgkmcnt(0)" ::: "memory"); SB();  // B(tt+1) arrived
    __builtin_amdgcn_s_barrier();
  }
  // ---- tail: tt=26 (no prefetch), tt=27 (last) ----
  {
    rdB(32768); rdA0(0);
    asm volatile("s_waitcnt lgkmcnt(0)" ::: "memory"); SB();
    mfmaLo();
    rdA1(0);
    asm volatile("s_waitcnt lgkmcnt(0)" ::: "memory"); SB();
    __builtin_amdgcn_s_barrier();
    cvtW(16384);                        // A(27)
    mfmaHi();
    asm volatile("s_waitcnt vmcnt(0) lgkmcnt(0)" ::: "memory"); SB();  // drain B(27)
    __builtin_amdgcn_s_barrier();

    rdB(49152); rdA0(16384);
    asm volatile("s_waitcnt lgkmcnt(0)" ::: "memory"); SB();
    mfmaLo();
    rdA1(16384);
    asm volatile("s_waitcnt lgkmcnt(0)" ::: "memory"); SB();
    mfmaHi();
  }

  // epilogue: relu -> bf16
#pragma unroll
  for (int m = 0; m < 8; ++m)
#pragma unroll
    for (int n = 0; n < 4; ++n)
#pragma unroll
      for (int q = 0; q < 4; ++q) {
        size_t row = rbase + wr * 128 + m * 16 + fg * 4 + q;
        size_t col = cbase + wc * 64 + n * 16 + fr;
        float vv = acc[m][n][q];
        vv = vv > 0.f ? vv : 0.f;
        Cp[row * 512 + col] = f2bf(vv);
      }
}

// Fused layers 2+3 (r5 version, proven): 64 rows x full 256 cols, 8 waves (2x4),
// BK=32, 16 steps, all-GLL dbuf, 2 blocks/CU.
__global__ __launch_bounds__(512, 4) void gemm23(
    const u16* __restrict__ m1, const u16* __restrict__ W1b,
    const u16* __restrict__ W2b, float* __restrict__ out)
{
  __shared__ u16 pool[20480];
  __shared__ u16 W2s[16][264];
  const int t = threadIdx.x, w = t >> 6, lane = t & 63;
  const size_t rbase = (size_t)blockIdx.x * 64;
  const int wr = w >> 2, wc = w & 3, fr = lane & 15, fg = lane >> 4;

  {
    int r = t >> 5, kc = (t & 31) * 8;
    *(int4*)&W2s[r][kc] = *(const int4*)(W2b + r * 256 + kc);
  }

  int aOff[2], bOff[4];
#pragma unroll
  for (int i = 0; i < 2; ++i) aOff[i] = swz((wr * 32 + i * 16 + fr) * 64 + fg * 16);
#pragma unroll
  for (int j = 0; j < 4; ++j) bOff[j] = swz((wc * 64 + j * 16 + fr) * 64 + fg * 16);

  const u16* aSrc = nullptr; int aDst = 0;
  if (w < 4) {
    int Dl = (w * 64 + lane) * 16;
    int Ul = swz(Dl);
    aSrc = m1 + (rbase + (Ul >> 6)) * 512 + ((Ul & 63) >> 1);
    aDst = (w * 64) * 16;
  }
  const u16* bSrc[2]; int bDst[2];
#pragma unroll
  for (int i = 0; i < 2; ++i) {
    int Dl = (w * 128 + i * 64 + lane) * 16;
    int Ul = swz(Dl);
    bSrc[i] = W1b + (Ul >> 6) * 512 + ((Ul & 63) >> 1);
    bDst[i] = 8192 + (w * 128 + i * 64) * 16;
  }

  f32x4 acc[2][4];
#pragma unroll
  for (int i = 0; i < 2; ++i)
#pragma unroll
    for (int j = 0; j < 4; ++j) acc[i][j] = (f32x4){0.f, 0.f, 0.f, 0.f};

  if (w < 4) GLL16(aSrc, (char*)pool + aDst);
#pragma unroll
  for (int i = 0; i < 2; ++i) GLL16(bSrc[i], (char*)pool + bDst[i]);

  for (int tt = 0; tt < 16; ++tt) {
    const int cur = tt & 1;
    const char* Asc = (const char*)pool + cur * 4096;
    const char* Bsc = (const char*)pool + 8192 + cur * 16384;
    asm volatile("s_waitcnt vmcnt(0)" ::: "memory");
    __syncthreads();

    if (tt < 15) {
      const int k0 = (tt + 1) * 32;
      if (w < 4) GLL16(aSrc + k0, (char*)pool + (cur ^ 1) * 4096 + aDst);
#pragma unroll
      for (int i = 0; i < 2; ++i)
        GLL16(bSrc[i] + k0, (char*)pool + (cur ^ 1) * 16384 + bDst[i]);
    }

    bhalf8 af[2], bfv[4];
#pragma unroll
    for (int i = 0; i < 2; ++i) af[i] = *(const bhalf8*)(Asc + aOff[i]);
#pragma unroll
    for (int j = 0; j < 4; ++j) bfv[j] = *(const bhalf8*)(Bsc + bOff[j]);
#pragma unroll
    for (int i = 0; i < 2; ++i)
#pragma unroll
      for (int j = 0; j < 4; ++j)
        acc[i][j] = __builtin_amdgcn_mfma_f32_16x16x32_bf16(af[i], bfv[j], acc[i][j], 0, 0, 0);
  }

  __syncthreads();
#pragma unroll
  for (int i = 0; i < 2; ++i)
#pragma unroll
    for (int j = 0; j < 4; ++j)
#pragma unroll
      for (int q = 0; q < 4; ++q) {
        int row = wr * 32 + i * 16 + fg * 4 + q;
        int col = wc * 64 + j * 16 + fr;
        float vv = acc[i][j][q];
        vv = vv > 0.f ? vv : 0.f;
        pool[row * 264 + col] = f2bf(vv);
      }
  __syncthreads();

  if (w < 4) {
    f32x4 acc3 = (f32x4){0.f, 0.f, 0.f, 0.f};
    const int arow = w * 16 + fr;
#pragma unroll
    for (int ks = 0; ks < 8; ++ks) {
      bhalf8 a = *(const bhalf8*)&pool[arow * 264 + ks * 32 + fg * 8];
      bhalf8 b = *(const bhalf8*)&W2s[fr][ks * 32 + fg * 8];
      acc3 = __builtin_amdgcn_mfma_f32_16x16x32_bf16(a, b, acc3, 0, 0, 0);
    }
    if (fr < 10) {
#pragma unroll
      for (int q = 0; q < 4; ++q) {
        size_t row = rbase + w * 16 + fg * 4 + q;
        float vv = acc3[q];
        out[row * 10 + fr] = vv > 0.f ? vv : 0.f;
      }
    }
  }
}

extern "C" void kernel_launch(void* const* d_in, const int* in_sizes, int n_in,
                              void* d_out, int out_size, void* d_ws, size_t ws_size,
                              hipStream_t stream) {
  const float* x  = (const float*)d_in[0];
  const float* W0 = (const float*)d_in[1];
  const float* W1 = (const float*)d_in[2];
  const float* W2 = (const float*)d_in[3];
  float* out = (float*)d_out;

  char* ws = (char*)d_ws;
  u16* m1  = (u16*)(ws);                    // 32768x512 bf16 = 33554432 B
  u16* W0b = (u16*)(ws + 33554432);         // 512x896 = 917504 B
  u16* W1b = (u16*)(ws + 34471936);         // 256x512 = 262144 B
  u16* W2b = (u16*)(ws + 34734080);         // 16x256  = 8192 B

  cvt_weights<<<dim3((W0E + W1E + W2E + 255) / 256), dim3(256), 0, stream>>>(
      W0, W1, W2, W0b, W1b, W2b);

  // m1 = relu(x @ W0^T): 128 row-tiles x 2 col-tiles = 256 blocks, 1/CU
  gemm1_8p<<<dim3(256), dim3(512), 0, stream>>>(x, W0b, m1);

  // out = relu(relu(m1 @ W1^T) @ W2^T)
  gemm23<<<dim3(512), dim3(512), 0, stream>>>(m1, W1b, W2b, out);
}